// Round 8
// baseline (81.270 us; speedup 1.0000x reference)
//
#include <hip/hip_runtime.h>

typedef short v4s __attribute__((ext_vector_type(4)));
typedef float v4f __attribute__((ext_vector_type(4)));

static __device__ __forceinline__ float bf16_to_f32(unsigned short u){
    return __uint_as_float(((unsigned int)u)<<16);
}
static __device__ __forceinline__ unsigned int f32_to_bf16_rne(float f){
    unsigned int b = __float_as_uint(f);
    b += 0x7fffu + ((b>>16)&1u);
    return b>>16;
}

// Packed f32x4 -> bf16x4 via v_cvt_pk_bf16_f32 with MFMA-hazard s_nop guards
// (validated rounds 2-7).
#define CVT_ACC_TO_B(lo, hi, acc) \
    asm("s_nop 1\n\t" \
        "v_cvt_pk_bf16_f32 %0, %2, %3\n\t" \
        "v_cvt_pk_bf16_f32 %1, %4, %5\n\t" \
        "s_nop 1" \
        : "=&v"(lo), "=&v"(hi) \
        : "v"(acc[0]), "v"(acc[1]), "v"(acc[2]), "v"(acc[3]))

#define SPW 4   // samples per wave

// ws layout:
// [0,2MB)          cores  bf16 [16][256][16][16] row-major = softplus(lc)*4096
// [2MB,4MB)        coresT bf16, inner 16x16 transposed
// [4MB,+64KB)      bars4 f32[4][16*256]  (partial column sums)
// [4MB+64KB,+4)    lognorm_total = log_norm_ref + 192*ln2

__global__ void k_softplus2(const float* __restrict__ lc,
                            unsigned short* __restrict__ cores,
                            unsigned short* __restrict__ coresT){
    int t = blockIdx.x * 256 + threadIdx.x;
    float4 v = ((const float4*)lc)[t];
    float s0 = (v.x>20.f)?v.x:log1pf(expf(v.x));
    float s1 = (v.y>20.f)?v.y:log1pf(expf(v.y));
    float s2 = (v.z>20.f)?v.z:log1pf(expf(v.z));
    float s3 = (v.w>20.f)?v.w:log1pf(expf(v.w));
    unsigned int w0 = f32_to_bf16_rne(s0*4096.f);
    unsigned int w1 = f32_to_bf16_rne(s1*4096.f);
    unsigned int w2 = f32_to_bf16_rne(s2*4096.f);
    unsigned int w3 = f32_to_bf16_rne(s3*4096.f);
    uint2 r; r.x = w0 | (w1<<16); r.y = w2 | (w3<<16);
    ((uint2*)cores)[t] = r;
    int e = t<<2;
    int mdbase = (e>>8)<<8;
    int row = (e>>4)&15, c = e&15;
    unsigned short* tp = coresT + mdbase + row;
    tp[(c+0)<<4] = (unsigned short)w0;
    tp[(c+1)<<4] = (unsigned short)w1;
    tp[(c+2)<<4] = (unsigned short)w2;
    tp[(c+3)<<4] = (unsigned short)w3;
}

// 64 blocks: block b sums d-range [64*(b&3), +64) of mode b>>2 -> bars4[b&3].
__global__ void k_bars3(const unsigned short* __restrict__ cores, float* __restrict__ bars4){
    int b = blockIdx.x, t = threadIdx.x;
    int m = b>>2, dq = b&3;
    const unsigned short* p = cores + m*65536 + dq*64*256 + t;
    float s = 0.f;
    #pragma unroll 16
    for (int d=0; d<64; d++) s += bf16_to_f32(p[d*256]);
    bars4[dq*4096 + m*256 + t] = s;
}

__global__ void k_norm2(const float* __restrict__ bars4, float* __restrict__ lognorm){
    __shared__ float sbars[16*256];
    __shared__ float cur[256];
    int t = threadIdx.x, i = t>>4, j = t&15;
    for (int m=0;m<16;m++){
        int o = m*256 + t;
        sbars[o] = bars4[o] + bars4[4096+o] + bars4[8192+o] + bars4[12288+o];
    }
    cur[t] = (i==j)?1.f:0.f;
    __syncthreads();
    for (int m=0;m<16;m++){
        float s = 0.f;
        #pragma unroll
        for (int k=0;k<16;k++) s += cur[i*16+k]*sbars[m*256 + k*16 + j];
        s *= 0.000244140625f; // 2^-12 cancels the 4096x core scale
        __syncthreads();
        cur[t] = s;
        __syncthreads();
    }
    if (t==0){
        float tr=0.f;
        #pragma unroll
        for (int k=0;k<16;k++) tr += cur[k*17];
        lognorm[0] = logf(tr) + 192.0f*0.69314718055994531f; // + log(4096^16)
    }
}

// Gathers with wave-uniform (SGPR) indices (validated round 7).
static __device__ __forceinline__ void gather_s(uint2* F, const int* __restrict__ ip,
        const unsigned short* __restrict__ cores,
        const unsigned short* __restrict__ coresT, int laneoff){
    #pragma unroll
    for (int k=0;k<16;k++){
        int ix = ip[k];                                // scalar load
        const unsigned short* tp = (k&1)? coresT : cores;
        F[k] = *(const uint2*)(tp + (((k<<8)|ix)<<8) + laneoff);
    }
}

// Binary-tree trace, split in two halves (math identical to validated rounds 4-7).
// A-frag(X) == B-frag(X^T); MFMA D-frag == B-frag(D).
static __device__ __forceinline__ void tree_level1(const uint2* F,
        unsigned int* c1lo, unsigned int* c1hi){
    #pragma unroll
    for (int i=0;i<8;i++){
        union{uint2 u; v4s v;} A,B;
        if (i&1){ A.u=F[2*i];   B.u=F[2*i+1]; }  // right-oriented
        else    { A.u=F[2*i+1]; B.u=F[2*i];   }  // left-oriented (P^T)
        v4f z={0.f,0.f,0.f,0.f};
        v4f acc=__builtin_amdgcn_mfma_f32_16x16x16bf16_1k(A.v,B.v,z,0,0,0);
        CVT_ACC_TO_B(c1lo[i],c1hi[i],acc);
    }
}
static __device__ __forceinline__ float tree_level23(const unsigned int* c1lo,
        const unsigned int* c1hi){
    unsigned int c2lo[4], c2hi[4];
    #pragma unroll
    for (int j=0;j<4;j++){
        union{uint2 u; v4s v;} A,B;
        if (j&1){ A.u=make_uint2(c1lo[2*j],c1hi[2*j]);     B.u=make_uint2(c1lo[2*j+1],c1hi[2*j+1]); }
        else    { A.u=make_uint2(c1lo[2*j+1],c1hi[2*j+1]); B.u=make_uint2(c1lo[2*j],c1hi[2*j]);     }
        v4f z={0.f,0.f,0.f,0.f};
        v4f acc=__builtin_amdgcn_mfma_f32_16x16x16bf16_1k(A.v,B.v,z,0,0,0);
        CVT_ACC_TO_B(c2lo[j],c2hi[j],acc);
    }
    union{uint2 u; v4s v;} A0,B0,A1,B1;
    A0.u=make_uint2(c2lo[1],c2hi[1]); B0.u=make_uint2(c2lo[0],c2hi[0]);
    A1.u=make_uint2(c2lo[2],c2hi[2]); B1.u=make_uint2(c2lo[3],c2hi[3]);
    v4f z={0.f,0.f,0.f,0.f};
    v4f aL=__builtin_amdgcn_mfma_f32_16x16x16bf16_1k(A0.v,B0.v,z,0,0,0);
    v4f aR=__builtin_amdgcn_mfma_f32_16x16x16bf16_1k(A1.v,B1.v,z,0,0,0);
    return aL[0]*aR[0]+aL[1]*aR[1]+aL[2]*aR[2]+aL[3]*aR[3];
}

__global__ __launch_bounds__(256) void k_chain7(const int* __restrict__ idx,
    const unsigned short* __restrict__ cores, const unsigned short* __restrict__ coresT,
    const float* __restrict__ lognorm, float* __restrict__ out)
{
    const int lane = threadIdx.x & 63;
    const int wq   = __builtin_amdgcn_readfirstlane(threadIdx.x >> 6);
    const int wave = (blockIdx.x<<2) + wq;
    const int col  = lane & 15;
    const int laneoff = col*16 + (((lane>>4)&3)<<2);
    const float L = lognorm[0];
    const int s0 = wave * SPW;
    const int* __restrict__ ip = idx + (s0<<4);

    uint2 F[16];
    unsigned int c1lo[8], c1hi[8];
    float d0,d1,d2,d3;

    // software pipeline: level1 consumes F -> refill F for next sample ->
    // sched_barrier pins the loads above level23 (anti-sinking, rounds 4/7 lesson).
    gather_s(F, ip, cores, coresT, laneoff);

    tree_level1(F, c1lo, c1hi);
    gather_s(F, ip+16, cores, coresT, laneoff);
    __builtin_amdgcn_sched_barrier(0);
    d0 = tree_level23(c1lo, c1hi);

    tree_level1(F, c1lo, c1hi);
    gather_s(F, ip+32, cores, coresT, laneoff);
    __builtin_amdgcn_sched_barrier(0);
    d1 = tree_level23(c1lo, c1hi);

    tree_level1(F, c1lo, c1hi);
    gather_s(F, ip+48, cores, coresT, laneoff);
    __builtin_amdgcn_sched_barrier(0);
    d2 = tree_level23(c1lo, c1hi);

    tree_level1(F, c1lo, c1hi);
    d3 = tree_level23(c1lo, c1hi);

    // batched butterfly: 4 independent shfl chains -> DS-pipe ILP 4
    #pragma unroll
    for (int off=32; off>0; off>>=1){
        d0 += __shfl_xor(d0, off, 64);
        d1 += __shfl_xor(d1, off, 64);
        d2 += __shfl_xor(d2, off, 64);
        d3 += __shfl_xor(d3, off, 64);
    }
    float res = (lane==0)?d0:(lane==1)?d1:(lane==2)?d2:(lane==3)?d3:0.f;

    if (lane < SPW){
        float o;
        if (!(L > -1e30f && L < 1e30f)) o = -5555.0f;   // lognorm bad
        else if (res > 0.f)             o = logf(res) - L;
        else                            o = -6666.0f;   // non-positive trace
        out[s0 + lane] = o;
    }
}

extern "C" void kernel_launch(void* const* d_in, const int* in_sizes, int n_in,
                              void* d_out, int out_size, void* d_ws, size_t ws_size,
                              hipStream_t stream)
{
    const int*   idx = (const int*)d_in[0];
    const float* lc  = (const float*)d_in[1];
    float* out = (float*)d_out;

    const size_t CORES_B = (size_t)16*256*256*2;                 // 2MB each table
    const size_t BARS4_B = (size_t)4*16*256*4;                   // 64KB
    const size_t WS_NEED = 2*CORES_B + BARS4_B + 4;
    if (ws_size < WS_NEED) return;   // signature: out stays 0 -> absmax ~= 89

    unsigned short* cores  = (unsigned short*)d_ws;
    unsigned short* coresT = (unsigned short*)((char*)d_ws + CORES_B);
    float* bars4   = (float*)((char*)d_ws + 2*CORES_B);
    float* lognorm = (float*)((char*)d_ws + 2*CORES_B + BARS4_B);

    k_softplus2<<<1024, 256, 0, stream>>>(lc, cores, coresT);
    k_bars3    <<<64,   256, 0, stream>>>(cores, bars4);
    k_norm2    <<<1,    256, 0, stream>>>(bars4, lognorm);
    int nblocks = out_size / (SPW*4);   // 4 waves/block -> 8192 blocks
    k_chain7   <<<nblocks, 256, 0, stream>>>(idx, cores, coresT, lognorm, out);
}

// Round 9
// 81.216 us; speedup vs baseline: 1.0007x; 1.0007x over previous
//
#include <hip/hip_runtime.h>

typedef short v4s __attribute__((ext_vector_type(4)));
typedef float v4f __attribute__((ext_vector_type(4)));
typedef unsigned int v2u __attribute__((ext_vector_type(2)));

union FU { v2u u; v4s s; };

static __device__ __forceinline__ float bf16_to_f32(unsigned short u){
    return __uint_as_float(((unsigned int)u)<<16);
}
static __device__ __forceinline__ unsigned int f32_to_bf16_rne(float f){
    unsigned int b = __float_as_uint(f);
    b += 0x7fffu + ((b>>16)&1u);
    return b>>16;
}

// Packed f32x4 -> bf16x4 via v_cvt_pk_bf16_f32 with MFMA-hazard s_nop guards
// (validated rounds 2-8).
#define CVT_ACC_TO_B(lo, hi, acc) \
    asm("s_nop 1\n\t" \
        "v_cvt_pk_bf16_f32 %0, %2, %3\n\t" \
        "v_cvt_pk_bf16_f32 %1, %4, %5\n\t" \
        "s_nop 1" \
        : "=&v"(lo), "=&v"(hi) \
        : "v"(acc[0]), "v"(acc[1]), "v"(acc[2]), "v"(acc[3]))

// Manual load-retirement wait (T4 counted-vmcnt) + rule-18 scheduling fence.
#define VMWAIT(n) do{ asm volatile("s_waitcnt vmcnt(" #n ")" ::: "memory"); \
                      __builtin_amdgcn_sched_barrier(0); }while(0)

#define SPW 4   // samples per wave

// ws layout:
// [0,2MB)          cores  bf16 [16][256][16][16] row-major = softplus(lc)*4096
// [2MB,4MB)        coresT bf16, inner 16x16 transposed
// [4MB,+64KB)      bars4 f32[4][16*256]  (partial column sums)
// [4MB+64KB,+4)    lognorm_total = log_norm_ref + 192*ln2

__global__ void k_softplus2(const float* __restrict__ lc,
                            unsigned short* __restrict__ cores,
                            unsigned short* __restrict__ coresT){
    int t = blockIdx.x * 256 + threadIdx.x;
    float4 v = ((const float4*)lc)[t];
    float s0 = (v.x>20.f)?v.x:log1pf(expf(v.x));
    float s1 = (v.y>20.f)?v.y:log1pf(expf(v.y));
    float s2 = (v.z>20.f)?v.z:log1pf(expf(v.z));
    float s3 = (v.w>20.f)?v.w:log1pf(expf(v.w));
    unsigned int w0 = f32_to_bf16_rne(s0*4096.f);
    unsigned int w1 = f32_to_bf16_rne(s1*4096.f);
    unsigned int w2 = f32_to_bf16_rne(s2*4096.f);
    unsigned int w3 = f32_to_bf16_rne(s3*4096.f);
    uint2 r; r.x = w0 | (w1<<16); r.y = w2 | (w3<<16);
    ((uint2*)cores)[t] = r;
    int e = t<<2;
    int mdbase = (e>>8)<<8;
    int row = (e>>4)&15, c = e&15;
    unsigned short* tp = coresT + mdbase + row;
    tp[(c+0)<<4] = (unsigned short)w0;
    tp[(c+1)<<4] = (unsigned short)w1;
    tp[(c+2)<<4] = (unsigned short)w2;
    tp[(c+3)<<4] = (unsigned short)w3;
}

__global__ void k_bars3(const unsigned short* __restrict__ cores, float* __restrict__ bars4){
    int b = blockIdx.x, t = threadIdx.x;
    int m = b>>2, dq = b&3;
    const unsigned short* p = cores + m*65536 + dq*64*256 + t;
    float s = 0.f;
    #pragma unroll 16
    for (int d=0; d<64; d++) s += bf16_to_f32(p[d*256]);
    bars4[dq*4096 + m*256 + t] = s;
}

__global__ void k_norm2(const float* __restrict__ bars4, float* __restrict__ lognorm){
    __shared__ float sbars[16*256];
    __shared__ float cur[256];
    int t = threadIdx.x, i = t>>4, j = t&15;
    for (int m=0;m<16;m++){
        int o = m*256 + t;
        sbars[o] = bars4[o] + bars4[4096+o] + bars4[8192+o] + bars4[12288+o];
    }
    cur[t] = (i==j)?1.f:0.f;
    __syncthreads();
    for (int m=0;m<16;m++){
        float s = 0.f;
        #pragma unroll
        for (int k=0;k<16;k++) s += cur[i*16+k]*sbars[m*256 + k*16 + j];
        s *= 0.000244140625f; // 2^-12 cancels the 4096x core scale
        __syncthreads();
        cur[t] = s;
        __syncthreads();
    }
    if (t==0){
        float tr=0.f;
        #pragma unroll
        for (int k=0;k<16;k++) tr += cur[k*17];
        lognorm[0] = logf(tr) + 192.0f*0.69314718055994531f; // + log(4096^16)
    }
}

// Issue 16 gather loads via volatile asm (guaranteed program order, NOT
// compiler-sinkable). base is wave-uniform SGPR math; voff is the only VGPR.
// Consumers must VMWAIT before reading F.
static __device__ __forceinline__ void gather_issue(v2u* F, const int* I,
        const unsigned short* __restrict__ cores,
        const unsigned short* __restrict__ coresT, unsigned int voff){
    #pragma unroll
    for (int k=0;k<16;k++){
        const unsigned short* tp = (k&1)? coresT : cores;
        const unsigned short* base = tp + (((k<<8)|I[k])<<8);
        asm volatile("global_load_dwordx2 %0, %1, %2"
                     : "=&v"(F[k]) : "v"(voff), "s"(base));
    }
}

// Binary-tree trace halves (math validated rounds 4-8).
// A-frag(X) == B-frag(X^T); MFMA D-frag == B-frag(D).
static __device__ __forceinline__ void tree_level1(const v2u* F,
        unsigned int* c1lo, unsigned int* c1hi){
    #pragma unroll
    for (int i=0;i<8;i++){
        FU A,B;
        if (i&1){ A.u=F[2*i];   B.u=F[2*i+1]; }  // right-oriented
        else    { A.u=F[2*i+1]; B.u=F[2*i];   }  // left-oriented (P^T)
        v4f z={0.f,0.f,0.f,0.f};
        v4f acc=__builtin_amdgcn_mfma_f32_16x16x16bf16_1k(A.s,B.s,z,0,0,0);
        CVT_ACC_TO_B(c1lo[i],c1hi[i],acc);
    }
}
static __device__ __forceinline__ float tree_level23(const unsigned int* c1lo,
        const unsigned int* c1hi){
    unsigned int c2lo[4], c2hi[4];
    #pragma unroll
    for (int j=0;j<4;j++){
        FU A,B;
        if (j&1){ A.u=(v2u){c1lo[2*j],c1hi[2*j]};     B.u=(v2u){c1lo[2*j+1],c1hi[2*j+1]}; }
        else    { A.u=(v2u){c1lo[2*j+1],c1hi[2*j+1]}; B.u=(v2u){c1lo[2*j],c1hi[2*j]};     }
        v4f z={0.f,0.f,0.f,0.f};
        v4f acc=__builtin_amdgcn_mfma_f32_16x16x16bf16_1k(A.s,B.s,z,0,0,0);
        CVT_ACC_TO_B(c2lo[j],c2hi[j],acc);
    }
    FU A0,B0,A1,B1;
    A0.u=(v2u){c2lo[1],c2hi[1]}; B0.u=(v2u){c2lo[0],c2hi[0]};
    A1.u=(v2u){c2lo[2],c2hi[2]}; B1.u=(v2u){c2lo[3],c2hi[3]};
    v4f z={0.f,0.f,0.f,0.f};
    v4f aL=__builtin_amdgcn_mfma_f32_16x16x16bf16_1k(A0.s,B0.s,z,0,0,0);
    v4f aR=__builtin_amdgcn_mfma_f32_16x16x16bf16_1k(A1.s,B1.s,z,0,0,0);
    return aL[0]*aR[0]+aL[1]*aR[1]+aL[2]*aR[2]+aL[3]*aR[3];
}

__global__ __launch_bounds__(256) void k_chain8(const int* __restrict__ idx,
    const unsigned short* __restrict__ cores, const unsigned short* __restrict__ coresT,
    const float* __restrict__ lognorm, float* __restrict__ out)
{
    const int lane = threadIdx.x & 63;
    const int wq   = __builtin_amdgcn_readfirstlane(threadIdx.x >> 6);
    const int wave = (blockIdx.x<<2) + wq;
    const int col  = lane & 15;
    const unsigned int voff = (unsigned int)((col*16 + (((lane>>4)&3)<<2))*2); // bytes
    const int s0 = wave * SPW;
    const int* __restrict__ ip = idx + (s0<<4);

    // all 64 mode-indices up front: 4x s_load_dwordx16-mergeable, one miss stall
    int I[64];
    #pragma unroll
    for (int k=0;k<64;k++) I[k] = ip[k];
    __builtin_amdgcn_sched_barrier(0);

    const float L = lognorm[0];

    v2u FA[16], FB[16];
    unsigned int c1lo[8], c1hi[8];
    float d0,d1,d2,d3;

    gather_issue(FA, I+0 , cores, coresT, voff);   // 16 outstanding
    gather_issue(FB, I+16, cores, coresT, voff);   // 32 outstanding

    VMWAIT(16);                                    // FA(s0) retired
    tree_level1(FA, c1lo, c1hi);
    gather_issue(FA, I+32, cores, coresT, voff);   // prefetch s2 under level23
    d0 = tree_level23(c1lo, c1hi);

    VMWAIT(16);                                    // FB(s1) retired (FIFO)
    tree_level1(FB, c1lo, c1hi);
    gather_issue(FB, I+48, cores, coresT, voff);   // prefetch s3
    d1 = tree_level23(c1lo, c1hi);

    VMWAIT(16);                                    // FA(s2) retired
    tree_level1(FA, c1lo, c1hi);
    d2 = tree_level23(c1lo, c1hi);

    VMWAIT(0);                                     // FB(s3) retired
    tree_level1(FB, c1lo, c1hi);
    d3 = tree_level23(c1lo, c1hi);

    // batched butterfly: 4 independent chains (validated round 8)
    #pragma unroll
    for (int off=32; off>0; off>>=1){
        d0 += __shfl_xor(d0, off, 64);
        d1 += __shfl_xor(d1, off, 64);
        d2 += __shfl_xor(d2, off, 64);
        d3 += __shfl_xor(d3, off, 64);
    }
    float res = (lane==0)?d0:(lane==1)?d1:(lane==2)?d2:(lane==3)?d3:0.f;

    if (lane < SPW){
        float o;
        if (!(L > -1e30f && L < 1e30f)) o = -5555.0f;   // lognorm bad
        else if (res > 0.f)             o = logf(res) - L;
        else                            o = -6666.0f;   // non-positive trace
        out[s0 + lane] = o;
    }
}

extern "C" void kernel_launch(void* const* d_in, const int* in_sizes, int n_in,
                              void* d_out, int out_size, void* d_ws, size_t ws_size,
                              hipStream_t stream)
{
    const int*   idx = (const int*)d_in[0];
    const float* lc  = (const float*)d_in[1];
    float* out = (float*)d_out;

    const size_t CORES_B = (size_t)16*256*256*2;                 // 2MB each table
    const size_t BARS4_B = (size_t)4*16*256*4;                   // 64KB
    const size_t WS_NEED = 2*CORES_B + BARS4_B + 4;
    if (ws_size < WS_NEED) return;   // signature: out stays 0 -> absmax ~= 89

    unsigned short* cores  = (unsigned short*)d_ws;
    unsigned short* coresT = (unsigned short*)((char*)d_ws + CORES_B);
    float* bars4   = (float*)((char*)d_ws + 2*CORES_B);
    float* lognorm = (float*)((char*)d_ws + 2*CORES_B + BARS4_B);

    k_softplus2<<<1024, 256, 0, stream>>>(lc, cores, coresT);
    k_bars3    <<<64,   256, 0, stream>>>(cores, bars4);
    k_norm2    <<<1,    256, 0, stream>>>(bars4, lognorm);
    int nblocks = out_size / (SPW*4);   // 4 waves/block -> 8192 blocks
    k_chain8   <<<nblocks, 256, 0, stream>>>(idx, cores, coresT, lognorm, out);
}